// Round 1
// baseline (2385.351 us; speedup 1.0000x reference)
//
#include <hip/hip_runtime.h>

#define N_NODES 50000
#define N_EDGES 640000
#define D 128

// ---------------------------------------------------------------------------
// Degree: cnt[dst] += 1 per edge (computed once, reused by both layers)
// ---------------------------------------------------------------------------
__global__ void deg_kernel(const int* __restrict__ dst, float* __restrict__ cnt) {
    int e = blockIdx.x * blockDim.x + threadIdx.x;
    if (e < N_EDGES) atomicAdd(&cnt[dst[e]], 1.0f);
}

// ---------------------------------------------------------------------------
// Scatter-add: agg[dst, :] += feat[src, :]. 32 threads per edge, float4 each.
// ---------------------------------------------------------------------------
__global__ void scatter_kernel(const float* __restrict__ feat,
                               const int* __restrict__ src,
                               const int* __restrict__ dst,
                               float* __restrict__ agg) {
    int gid = blockIdx.x * blockDim.x + threadIdx.x;
    int e = gid >> 5;
    if (e >= N_EDGES) return;
    int c = (gid & 31) * 4;
    int s = src[e], d = dst[e];
    const float4 v = *reinterpret_cast<const float4*>(&feat[(size_t)s * D + c]);
    float* a = &agg[(size_t)d * D + c];
    atomicAdd(a + 0, v.x);
    atomicAdd(a + 1, v.y);
    atomicAdd(a + 2, v.z);
    atomicAdd(a + 3, v.w);
}

// ---------------------------------------------------------------------------
// Fused SAGE dense step: out = [relu]( (agg/max(cnt,1)) @ Wl + bias + feat @ Wr )
// Block = 128 threads (2 waves), each block owns 16 rows; rows staged in LDS,
// W read from global (128 KB total, L2-resident). Thread j owns column j for
// all 16 rows (acc[16] in VGPRs).
// ---------------------------------------------------------------------------
template <bool RELU>
__global__ __launch_bounds__(128) void sage_gemm(
    const float* __restrict__ feat,   // [N, D] root features
    const float* __restrict__ agg,    // [N, D] neighbor sums
    const float* __restrict__ cnt,    // [N]
    const float* __restrict__ Wl,     // [D, D]
    const float* __restrict__ bias,   // [D]
    const float* __restrict__ Wr,     // [D, D]
    float* __restrict__ out)          // [N, D]
{
    constexpr int ROWS = 16;
    __shared__ float sm_mean[ROWS][D];
    __shared__ float sm_x[ROWS][D];
    const int t = threadIdx.x;            // 0..127
    const int row0 = blockIdx.x * ROWS;   // N_NODES % 16 == 0, always in-bounds

    // Stage 16 rows of mean (= agg * 1/max(cnt,1)) and feat into LDS, float4.
#pragma unroll
    for (int i = 0; i < 4; ++i) {
        int v = i * 128 + t;              // float4 slot 0..511
        int r = v >> 5;                   // 32 float4 per row
        int c4 = (v & 31) * 4;
        int node = row0 + r;
        float4 a = *reinterpret_cast<const float4*>(&agg[(size_t)node * D + c4]);
        float4 xx = *reinterpret_cast<const float4*>(&feat[(size_t)node * D + c4]);
        float inv = 1.0f / fmaxf(cnt[node], 1.0f);
        *reinterpret_cast<float4*>(&sm_mean[r][c4]) =
            make_float4(a.x * inv, a.y * inv, a.z * inv, a.w * inv);
        *reinterpret_cast<float4*>(&sm_x[r][c4]) = xx;
    }
    __syncthreads();

    const int j = t;
    float acc[ROWS];
    const float bj = bias[j];
#pragma unroll
    for (int r = 0; r < ROWS; ++r) acc[r] = bj;

    for (int k = 0; k < D; k += 4) {
        // column j of Wl/Wr for 4 consecutive k (coalesced across lanes)
        float wl0 = Wl[(k + 0) * D + j], wl1 = Wl[(k + 1) * D + j];
        float wl2 = Wl[(k + 2) * D + j], wl3 = Wl[(k + 3) * D + j];
        float wr0 = Wr[(k + 0) * D + j], wr1 = Wr[(k + 1) * D + j];
        float wr2 = Wr[(k + 2) * D + j], wr3 = Wr[(k + 3) * D + j];
#pragma unroll
        for (int r = 0; r < ROWS; ++r) {
            float4 m = *reinterpret_cast<const float4*>(&sm_mean[r][k]);
            float4 xv = *reinterpret_cast<const float4*>(&sm_x[r][k]);
            acc[r] += m.x * wl0 + m.y * wl1 + m.z * wl2 + m.w * wl3
                    + xv.x * wr0 + xv.y * wr1 + xv.z * wr2 + xv.w * wr3;
        }
    }

#pragma unroll
    for (int r = 0; r < ROWS; ++r) {
        float v = acc[r];
        if (RELU) v = fmaxf(v, 0.0f);
        out[(size_t)(row0 + r) * D + j] = v;
    }
}

// ---------------------------------------------------------------------------
extern "C" void kernel_launch(void* const* d_in, const int* in_sizes, int n_in,
                              void* d_out, int out_size, void* d_ws, size_t ws_size,
                              hipStream_t stream) {
    const float* x   = (const float*)d_in[0];
    const int*   ei  = (const int*)d_in[1];
    const float* W1l = (const float*)d_in[2];
    const float* b1  = (const float*)d_in[3];
    const float* W1r = (const float*)d_in[4];
    const float* W2l = (const float*)d_in[5];
    const float* b2  = (const float*)d_in[6];
    const float* W2r = (const float*)d_in[7];
    float* out = (float*)d_out;

    const int* src = ei;             // edge_index[0]
    const int* dst = ei + N_EDGES;   // edge_index[1]

    float* cnt = (float*)d_ws;                       // N floats (padded to 51200)
    float* agg = cnt + 51200;                        // N*D floats
    float* h   = agg + (size_t)N_NODES * D;          // N*D floats

    hipMemsetAsync(cnt, 0, N_NODES * sizeof(float), stream);
    hipMemsetAsync(agg, 0, (size_t)N_NODES * D * sizeof(float), stream);

    deg_kernel<<<(N_EDGES + 255) / 256, 256, 0, stream>>>(dst, cnt);

    // ---- layer 1 ----
    scatter_kernel<<<(N_EDGES * 32) / 256, 256, 0, stream>>>(x, src, dst, agg);
    sage_gemm<true><<<N_NODES / 16, 128, 0, stream>>>(x, agg, cnt, W1l, b1, W1r, h);

    // ---- layer 2 ----
    hipMemsetAsync(agg, 0, (size_t)N_NODES * D * sizeof(float), stream);
    scatter_kernel<<<(N_EDGES * 32) / 256, 256, 0, stream>>>(h, src, dst, agg);
    sage_gemm<false><<<N_NODES / 16, 128, 0, stream>>>(h, agg, cnt, W2l, b2, W2r, out);
}

// Round 2
// 460.143 us; speedup vs baseline: 5.1839x; 5.1839x over previous
//
#include <hip/hip_runtime.h>

#define N_NODES 50000
#define N_EDGES 640000
#define D 128

// ---------------------------------------------------------------------------
// Degree histogram: deg[dst]++ per edge (int atomics, one-time)
// ---------------------------------------------------------------------------
__global__ void deg_kernel(const int* __restrict__ dst, int* __restrict__ deg) {
    int e = blockIdx.x * blockDim.x + threadIdx.x;
    if (e < N_EDGES) atomicAdd(&deg[dst[e]], 1);
}

// ---------------------------------------------------------------------------
// Single-block exclusive scan over deg -> row_off (and cursor copy).
// Thread t serially owns CH contiguous elements; 1024 partials scanned in LDS.
// ---------------------------------------------------------------------------
__global__ __launch_bounds__(1024) void scan_kernel(const int* __restrict__ deg,
                                                    int* __restrict__ row_off,
                                                    int* __restrict__ cursor) {
    constexpr int CH = (N_NODES + 1023) / 1024;  // 49
    __shared__ int sdata[1024];
    const int t = threadIdx.x;
    const int base = t * CH;

    int sum = 0;
    for (int i = 0; i < CH; ++i) {
        int idx = base + i;
        if (idx < N_NODES) sum += deg[idx];
    }
    sdata[t] = sum;
    __syncthreads();

    // Hillis-Steele inclusive scan over 1024 partials
    int x = sum;
    for (int off = 1; off < 1024; off <<= 1) {
        int y = (t >= off) ? sdata[t - off] : 0;
        __syncthreads();
        x += y;
        sdata[t] = x;
        __syncthreads();
    }
    int excl = x - sum;  // exclusive prefix of this thread's chunk

    int off = excl;
    for (int i = 0; i < CH; ++i) {
        int idx = base + i;
        if (idx < N_NODES) {
            row_off[idx] = off;
            cursor[idx] = off;
            off += deg[idx];
        }
    }
    if (t == 1023) row_off[N_NODES] = off;  // == N_EDGES
}

// ---------------------------------------------------------------------------
// CSR fill: csr_src[cursor[dst[e]]++] = src[e] (int atomics, one-time)
// ---------------------------------------------------------------------------
__global__ void fill_csr(const int* __restrict__ src, const int* __restrict__ dst,
                         int* __restrict__ cursor, int* __restrict__ csr_src) {
    int e = blockIdx.x * blockDim.x + threadIdx.x;
    if (e < N_EDGES) {
        int pos = atomicAdd(&cursor[dst[e]], 1);
        csr_src[pos] = src[e];
    }
}

// ---------------------------------------------------------------------------
// Gather-aggregate: mean[node, :] = (1/max(deg,1)) * sum_{k} feat[csr_src[k], :]
// 32 lanes per node, float4 per lane (32*4 = 128 cols). No atomics.
// ---------------------------------------------------------------------------
__global__ __launch_bounds__(256) void gather_kernel(const float* __restrict__ feat,
                                                     const int* __restrict__ row_off,
                                                     const int* __restrict__ csr_src,
                                                     float* __restrict__ mean) {
    int gid = blockIdx.x * blockDim.x + threadIdx.x;
    int node = gid >> 5;
    if (node >= N_NODES) return;
    int c = (gid & 31) * 4;
    int beg = row_off[node];
    int end = row_off[node + 1];

    float4 s = make_float4(0.f, 0.f, 0.f, 0.f);
    for (int k = beg; k < end; ++k) {
        int srcn = csr_src[k];
        float4 v = *reinterpret_cast<const float4*>(&feat[(size_t)srcn * D + c]);
        s.x += v.x; s.y += v.y; s.z += v.z; s.w += v.w;
    }
    float inv = 1.0f / fmaxf((float)(end - beg), 1.0f);
    *reinterpret_cast<float4*>(&mean[(size_t)node * D + c]) =
        make_float4(s.x * inv, s.y * inv, s.z * inv, s.w * inv);
}

// ---------------------------------------------------------------------------
// Fused SAGE dense step: out = [relu]( mean @ Wl + bias + feat @ Wr )
// Block = 128 threads, 16 rows staged in LDS; thread j owns output column j.
// ---------------------------------------------------------------------------
template <bool RELU>
__global__ __launch_bounds__(128) void sage_gemm(
    const float* __restrict__ feat,   // [N, D] root features
    const float* __restrict__ mean,   // [N, D] neighbor means
    const float* __restrict__ Wl,     // [D, D]
    const float* __restrict__ bias,   // [D]
    const float* __restrict__ Wr,     // [D, D]
    float* __restrict__ out)          // [N, D]
{
    constexpr int ROWS = 16;
    __shared__ float sm_mean[ROWS][D];
    __shared__ float sm_x[ROWS][D];
    const int t = threadIdx.x;            // 0..127
    const int row0 = blockIdx.x * ROWS;   // N_NODES % 16 == 0

#pragma unroll
    for (int i = 0; i < 4; ++i) {
        int v = i * 128 + t;              // float4 slot 0..511
        int r = v >> 5;
        int c4 = (v & 31) * 4;
        int node = row0 + r;
        *reinterpret_cast<float4*>(&sm_mean[r][c4]) =
            *reinterpret_cast<const float4*>(&mean[(size_t)node * D + c4]);
        *reinterpret_cast<float4*>(&sm_x[r][c4]) =
            *reinterpret_cast<const float4*>(&feat[(size_t)node * D + c4]);
    }
    __syncthreads();

    const int j = t;
    float acc[ROWS];
    const float bj = bias[j];
#pragma unroll
    for (int r = 0; r < ROWS; ++r) acc[r] = bj;

    for (int k = 0; k < D; k += 4) {
        float wl0 = Wl[(k + 0) * D + j], wl1 = Wl[(k + 1) * D + j];
        float wl2 = Wl[(k + 2) * D + j], wl3 = Wl[(k + 3) * D + j];
        float wr0 = Wr[(k + 0) * D + j], wr1 = Wr[(k + 1) * D + j];
        float wr2 = Wr[(k + 2) * D + j], wr3 = Wr[(k + 3) * D + j];
#pragma unroll
        for (int r = 0; r < ROWS; ++r) {
            float4 m = *reinterpret_cast<const float4*>(&sm_mean[r][k]);
            float4 xv = *reinterpret_cast<const float4*>(&sm_x[r][k]);
            acc[r] += m.x * wl0 + m.y * wl1 + m.z * wl2 + m.w * wl3
                    + xv.x * wr0 + xv.y * wr1 + xv.z * wr2 + xv.w * wr3;
        }
    }

#pragma unroll
    for (int r = 0; r < ROWS; ++r) {
        float v = acc[r];
        if (RELU) v = fmaxf(v, 0.0f);
        out[(size_t)(row0 + r) * D + j] = v;
    }
}

// ---------------------------------------------------------------------------
extern "C" void kernel_launch(void* const* d_in, const int* in_sizes, int n_in,
                              void* d_out, int out_size, void* d_ws, size_t ws_size,
                              hipStream_t stream) {
    const float* x   = (const float*)d_in[0];
    const int*   ei  = (const int*)d_in[1];
    const float* W1l = (const float*)d_in[2];
    const float* b1  = (const float*)d_in[3];
    const float* W1r = (const float*)d_in[4];
    const float* W2l = (const float*)d_in[5];
    const float* b2  = (const float*)d_in[6];
    const float* W2r = (const float*)d_in[7];
    float* out = (float*)d_out;

    const int* src = ei;             // edge_index[0]
    const int* dst = ei + N_EDGES;   // edge_index[1]

    // Workspace layout
    int*   deg     = (int*)d_ws;                       // 51200 ints
    int*   row_off = deg + 51200;                      // 51200 ints (N+1 used)
    int*   cursor  = row_off + 51200;                  // 51200 ints
    int*   csr_src = cursor + 51200;                   // 640000 ints
    float* mean    = (float*)(csr_src + N_EDGES);      // N*D floats
    float* h       = mean + (size_t)N_NODES * D;       // N*D floats

    // ---- one-time CSR build ----
    hipMemsetAsync(deg, 0, N_NODES * sizeof(int), stream);
    deg_kernel<<<(N_EDGES + 255) / 256, 256, 0, stream>>>(dst, deg);
    scan_kernel<<<1, 1024, 0, stream>>>(deg, row_off, cursor);
    fill_csr<<<(N_EDGES + 255) / 256, 256, 0, stream>>>(src, dst, cursor, csr_src);

    // ---- layer 1 ----
    gather_kernel<<<(N_NODES * 32 + 255) / 256, 256, 0, stream>>>(x, row_off, csr_src, mean);
    sage_gemm<true><<<N_NODES / 16, 128, 0, stream>>>(x, mean, W1l, b1, W1r, h);

    // ---- layer 2 ----
    gather_kernel<<<(N_NODES * 32 + 255) / 256, 256, 0, stream>>>(h, row_off, csr_src, mean);
    sage_gemm<false><<<N_NODES / 16, 128, 0, stream>>>(h, mean, W2l, b2, W2r, out);
}

// Round 3
// 350.035 us; speedup vs baseline: 6.8146x; 1.3146x over previous
//
#include <hip/hip_runtime.h>

#define N_NODES 50000
#define N_EDGES 640000
#define D 128

#define SCAN_BLOCK 256
#define SCAN_NBLK ((N_NODES + SCAN_BLOCK - 1) / SCAN_BLOCK)  // 196

// ---------------------------------------------------------------------------
// Degree histogram: deg[dst]++ per edge (int atomics, one-time)
// ---------------------------------------------------------------------------
__global__ void deg_kernel(const int* __restrict__ dst, int* __restrict__ deg) {
    int e = blockIdx.x * blockDim.x + threadIdx.x;
    if (e < N_EDGES) atomicAdd(&deg[dst[e]], 1);
}

// ---------------------------------------------------------------------------
// Hierarchical scan, step 1: per-block sums of deg (196 blocks x 256)
// ---------------------------------------------------------------------------
__global__ __launch_bounds__(SCAN_BLOCK) void scan_partial(const int* __restrict__ deg,
                                                           int* __restrict__ partial) {
    __shared__ int sm[SCAN_BLOCK];
    const int t = threadIdx.x;
    const int i = blockIdx.x * SCAN_BLOCK + t;
    sm[t] = (i < N_NODES) ? deg[i] : 0;
    __syncthreads();
#pragma unroll
    for (int off = SCAN_BLOCK / 2; off > 0; off >>= 1) {
        if (t < off) sm[t] += sm[t + off];
        __syncthreads();
    }
    if (t == 0) partial[blockIdx.x] = sm[0];
}

// ---------------------------------------------------------------------------
// Step 2: single-block scan over the 196 partials -> exclusive block offsets.
// Also writes row_off[N_NODES] = total (= N_EDGES).
// ---------------------------------------------------------------------------
__global__ __launch_bounds__(SCAN_BLOCK) void scan_offsets(const int* __restrict__ partial,
                                                           int* __restrict__ block_off,
                                                           int* __restrict__ row_off) {
    __shared__ int sm[SCAN_BLOCK];
    const int t = threadIdx.x;
    int v = (t < SCAN_NBLK) ? partial[t] : 0;
    sm[t] = v;
    __syncthreads();
    int x = v;
#pragma unroll
    for (int off = 1; off < SCAN_BLOCK; off <<= 1) {
        int y = (t >= off) ? sm[t - off] : 0;
        __syncthreads();
        x += y;
        sm[t] = x;
        __syncthreads();
    }
    if (t < SCAN_NBLK) block_off[t] = x - v;          // exclusive prefix
    if (t == SCAN_BLOCK - 1) row_off[N_NODES] = x;    // grand total
}

// ---------------------------------------------------------------------------
// Step 3: in-block exclusive scan + block offset -> row_off, cursor
// ---------------------------------------------------------------------------
__global__ __launch_bounds__(SCAN_BLOCK) void scan_final(const int* __restrict__ deg,
                                                         const int* __restrict__ block_off,
                                                         int* __restrict__ row_off,
                                                         int* __restrict__ cursor) {
    __shared__ int sm[SCAN_BLOCK];
    const int t = threadIdx.x;
    const int i = blockIdx.x * SCAN_BLOCK + t;
    int v = (i < N_NODES) ? deg[i] : 0;
    sm[t] = v;
    __syncthreads();
    int x = v;
#pragma unroll
    for (int off = 1; off < SCAN_BLOCK; off <<= 1) {
        int y = (t >= off) ? sm[t - off] : 0;
        __syncthreads();
        x += y;
        sm[t] = x;
        __syncthreads();
    }
    int excl = x - v + block_off[blockIdx.x];
    if (i < N_NODES) {
        row_off[i] = excl;
        cursor[i] = excl;
    }
}

// ---------------------------------------------------------------------------
// CSR fill: csr_src[cursor[dst[e]]++] = src[e] (int atomics, one-time)
// ---------------------------------------------------------------------------
__global__ void fill_csr(const int* __restrict__ src, const int* __restrict__ dst,
                         int* __restrict__ cursor, int* __restrict__ csr_src) {
    int e = blockIdx.x * blockDim.x + threadIdx.x;
    if (e < N_EDGES) {
        int pos = atomicAdd(&cursor[dst[e]], 1);
        csr_src[pos] = src[e];
    }
}

// ---------------------------------------------------------------------------
// Gather-aggregate: mean[node, :] = (1/max(deg,1)) * sum_{k} feat[csr_src[k], :]
// 32 lanes per node, float4 per lane (32*4 = 128 cols). No atomics.
// ---------------------------------------------------------------------------
__global__ __launch_bounds__(256) void gather_kernel(const float* __restrict__ feat,
                                                     const int* __restrict__ row_off,
                                                     const int* __restrict__ csr_src,
                                                     float* __restrict__ mean) {
    int gid = blockIdx.x * blockDim.x + threadIdx.x;
    int node = gid >> 5;
    if (node >= N_NODES) return;
    int c = (gid & 31) * 4;
    int beg = row_off[node];
    int end = row_off[node + 1];

    float4 s = make_float4(0.f, 0.f, 0.f, 0.f);
    for (int k = beg; k < end; ++k) {
        int srcn = csr_src[k];
        float4 v = *reinterpret_cast<const float4*>(&feat[(size_t)srcn * D + c]);
        s.x += v.x; s.y += v.y; s.z += v.z; s.w += v.w;
    }
    float inv = 1.0f / fmaxf((float)(end - beg), 1.0f);
    *reinterpret_cast<float4*>(&mean[(size_t)node * D + c]) =
        make_float4(s.x * inv, s.y * inv, s.z * inv, s.w * inv);
}

// ---------------------------------------------------------------------------
// Fused SAGE dense step: out = [relu]( mean @ Wl + bias + feat @ Wr )
// Block = 128 threads, 16 rows staged in LDS; thread j owns output column j.
// ---------------------------------------------------------------------------
template <bool RELU>
__global__ __launch_bounds__(128) void sage_gemm(
    const float* __restrict__ feat,   // [N, D] root features
    const float* __restrict__ mean,   // [N, D] neighbor means
    const float* __restrict__ Wl,     // [D, D]
    const float* __restrict__ bias,   // [D]
    const float* __restrict__ Wr,     // [D, D]
    float* __restrict__ out)          // [N, D]
{
    constexpr int ROWS = 16;
    __shared__ float sm_mean[ROWS][D];
    __shared__ float sm_x[ROWS][D];
    const int t = threadIdx.x;            // 0..127
    const int row0 = blockIdx.x * ROWS;   // N_NODES % 16 == 0

#pragma unroll
    for (int i = 0; i < 4; ++i) {
        int v = i * 128 + t;              // float4 slot 0..511
        int r = v >> 5;
        int c4 = (v & 31) * 4;
        int node = row0 + r;
        *reinterpret_cast<float4*>(&sm_mean[r][c4]) =
            *reinterpret_cast<const float4*>(&mean[(size_t)node * D + c4]);
        *reinterpret_cast<float4*>(&sm_x[r][c4]) =
            *reinterpret_cast<const float4*>(&feat[(size_t)node * D + c4]);
    }
    __syncthreads();

    const int j = t;
    float acc[ROWS];
    const float bj = bias[j];
#pragma unroll
    for (int r = 0; r < ROWS; ++r) acc[r] = bj;

    for (int k = 0; k < D; k += 4) {
        float wl0 = Wl[(k + 0) * D + j], wl1 = Wl[(k + 1) * D + j];
        float wl2 = Wl[(k + 2) * D + j], wl3 = Wl[(k + 3) * D + j];
        float wr0 = Wr[(k + 0) * D + j], wr1 = Wr[(k + 1) * D + j];
        float wr2 = Wr[(k + 2) * D + j], wr3 = Wr[(k + 3) * D + j];
#pragma unroll
        for (int r = 0; r < ROWS; ++r) {
            float4 m = *reinterpret_cast<const float4*>(&sm_mean[r][k]);
            float4 xv = *reinterpret_cast<const float4*>(&sm_x[r][k]);
            acc[r] += m.x * wl0 + m.y * wl1 + m.z * wl2 + m.w * wl3
                    + xv.x * wr0 + xv.y * wr1 + xv.z * wr2 + xv.w * wr3;
        }
    }

#pragma unroll
    for (int r = 0; r < ROWS; ++r) {
        float v = acc[r];
        if (RELU) v = fmaxf(v, 0.0f);
        out[(size_t)(row0 + r) * D + j] = v;
    }
}

// ---------------------------------------------------------------------------
extern "C" void kernel_launch(void* const* d_in, const int* in_sizes, int n_in,
                              void* d_out, int out_size, void* d_ws, size_t ws_size,
                              hipStream_t stream) {
    const float* x   = (const float*)d_in[0];
    const int*   ei  = (const int*)d_in[1];
    const float* W1l = (const float*)d_in[2];
    const float* b1  = (const float*)d_in[3];
    const float* W1r = (const float*)d_in[4];
    const float* W2l = (const float*)d_in[5];
    const float* b2  = (const float*)d_in[6];
    const float* W2r = (const float*)d_in[7];
    float* out = (float*)d_out;

    const int* src = ei;             // edge_index[0]
    const int* dst = ei + N_EDGES;   // edge_index[1]

    // Workspace layout
    int*   deg       = (int*)d_ws;                     // 51200 ints
    int*   row_off   = deg + 51200;                    // 51200 ints (N+1 used)
    int*   cursor    = row_off + 51200;                // 51200 ints
    int*   partial   = cursor + 51200;                 // 256 ints
    int*   block_off = partial + 256;                  // 256 ints
    int*   csr_src   = block_off + 256;                // 640000 ints
    float* mean      = (float*)(csr_src + N_EDGES);    // N*D floats
    float* h         = mean + (size_t)N_NODES * D;     // N*D floats

    // ---- one-time CSR build ----
    hipMemsetAsync(deg, 0, N_NODES * sizeof(int), stream);
    deg_kernel<<<(N_EDGES + 255) / 256, 256, 0, stream>>>(dst, deg);
    scan_partial<<<SCAN_NBLK, SCAN_BLOCK, 0, stream>>>(deg, partial);
    scan_offsets<<<1, SCAN_BLOCK, 0, stream>>>(partial, block_off, row_off);
    scan_final<<<SCAN_NBLK, SCAN_BLOCK, 0, stream>>>(deg, block_off, row_off, cursor);
    fill_csr<<<(N_EDGES + 255) / 256, 256, 0, stream>>>(src, dst, cursor, csr_src);

    // ---- layer 1 ----
    gather_kernel<<<(N_NODES * 32 + 255) / 256, 256, 0, stream>>>(x, row_off, csr_src, mean);
    sage_gemm<true><<<N_NODES / 16, 128, 0, stream>>>(x, mean, W1l, b1, W1r, h);

    // ---- layer 2 ----
    gather_kernel<<<(N_NODES * 32 + 255) / 256, 256, 0, stream>>>(h, row_off, csr_src, mean);
    sage_gemm<false><<<N_NODES / 16, 128, 0, stream>>>(h, mean, W2l, b2, W2r, out);
}